// Round 15
// baseline (92.207 us; speedup 1.0000x reference)
//
#include <hip/hip_runtime.h>
#include <hip/hip_bf16.h>

typedef __attribute__((ext_vector_type(4))) float f32x4;
typedef __attribute__((ext_vector_type(8))) short bf16x8;
typedef __attribute__((ext_vector_type(8))) unsigned short ushort8;

#define EPSBN 1e-5f

__device__ __forceinline__ unsigned short f2bf(float f) {
  unsigned int u = __builtin_bit_cast(unsigned int, f);
  u += 0x7fffu + ((u >> 16) & 1u);
  return (unsigned short)(u >> 16);
}

__device__ __forceinline__ void gload_lds16(const unsigned short* g, unsigned short* l) {
  __builtin_amdgcn_global_load_lds(
      (const __attribute__((address_space(1))) void*)g,
      (__attribute__((address_space(3))) void*)l, 16, 0, 0);
}

// ---------- kernel 1: fused avg-pool + x -> bf16 pre-padded staging layout ----------
// xpad layout: [b][cg(32)][h_pad(34)][w_pad(34)][8c] bf16, zero border.
__global__ __launch_bounds__(256) void prep_kernel(const float* __restrict__ x,
                                                   float* __restrict__ avg,
                                                   unsigned short* __restrict__ xpad) {
  int blk = blockIdx.x;  // b*32 + cg
  int b = blk >> 5, cg = blk & 31;
  int t = threadIdx.x;
  int c = t >> 5, l32 = t & 31;
  __shared__ unsigned short lds_t[1024 * 9];  // [p][c] with pad-9 row (conflict-break)
  __shared__ float avg_lds[8];
  const float4* xb4 = reinterpret_cast<const float4*>(x) + ((size_t)(b * 256 + cg * 8 + c)) * 256;
  float s = 0.f;
#pragma unroll
  for (int i = 0; i < 8; ++i) {
    float4 v = xb4[l32 + 32 * i];
    s += v.x + v.y + v.z + v.w;
    int p = 4 * (l32 + 32 * i);
    lds_t[(p + 0) * 9 + c] = f2bf(v.x);
    lds_t[(p + 1) * 9 + c] = f2bf(v.y);
    lds_t[(p + 2) * 9 + c] = f2bf(v.z);
    lds_t[(p + 3) * 9 + c] = f2bf(v.w);
  }
#pragma unroll
  for (int off = 16; off >= 1; off >>= 1) s += __shfl_down(s, off, 32);
  if (l32 == 0) avg_lds[c] = s;
  __syncthreads();
  if (t < 8) avg[b * 256 + cg * 8 + t] = avg_lds[t] * (1.0f / 1024.0f);
  size_t obase = (size_t)blk * 1156 * 8;
  for (int sIdx = t; sIdx < 1156; sIdx += 256) {
    int h = sIdx / 34, w = sIdx % 34;
    ushort8 v;
    if (h >= 1 && h <= 32 && w >= 1 && w <= 32) {
      int p = (h - 1) * 32 + (w - 1);
#pragma unroll
      for (int cl = 0; cl < 8; ++cl) v[cl] = lds_t[p * 9 + cl];
    } else {
#pragma unroll
      for (int cl = 0; cl < 8; ++cl) v[cl] = 0;
    }
    *reinterpret_cast<ushort8*>(xpad + obase + (size_t)sIdx * 8) = v;
  }
}

// ---------- kernel 2: attention head -> att[B][4] ----------
__global__ __launch_bounds__(256) void att_kernel(
    const float* __restrict__ z, const float* __restrict__ avg,
    const float* __restrict__ w1, const float* __restrict__ gamma,
    const float* __restrict__ beta, const float* __restrict__ mean,
    const float* __restrict__ var, const float* __restrict__ w2,
    float* __restrict__ att) {
  int b = blockIdx.x, t = threadIdx.x;
  __shared__ __align__(16) float a[512];
  __shared__ float h[256];
  a[t] = z[b * 256 + t];
  a[t + 256] = avg[b * 256 + t];
  __syncthreads();
  const float4* wr = reinterpret_cast<const float4*>(w1 + (size_t)t * 512);
  const float4* a4 = reinterpret_cast<const float4*>(a);
  float s = 0.f;
#pragma unroll 4
  for (int j = 0; j < 128; ++j) {
    float4 wv = wr[j], av = a4[j];
    s += wv.x * av.x + wv.y * av.y + wv.z * av.z + wv.w * av.w;
  }
  s = (s - mean[t]) * rsqrtf(var[t] + EPSBN) * gamma[t] + beta[t];
  h[t] = fmaxf(s, 0.f);
  __syncthreads();
  int wv_ = t >> 6, lane = t & 63;
  const float* w2r = w2 + wv_ * 256;
  float p = h[lane] * w2r[lane] + h[lane + 64] * w2r[lane + 64] +
            h[lane + 128] * w2r[lane + 128] + h[lane + 192] * w2r[lane + 192];
#pragma unroll
  for (int off = 32; off >= 1; off >>= 1) p += __shfl_down(p, off);
  if (lane == 0) att[b * 4 + wv_] = 1.0f / (1.0f + expf(-p));
}

// ---------- kernel 3: mix weights via LDS transpose -> bf16 agg in conv A-layout ----------
// agg element index: ((((b*9+tap)*8+cc)*4+cblk)*256 + o)*8 + cl ; c = cc*32+cblk*8+cl
// 320 threads: phase1 = 9 exact float4 loads/thread; phase2 = 1 slot/thread (288 active).
#define MROW 291  // padded LDS row stride (floats) for bank decorrelation
__global__ __launch_bounds__(320) void mix_kernel(
    const float* __restrict__ weight, const float* __restrict__ statw,
    const float* __restrict__ att, unsigned short* __restrict__ agg) {
  int cc = blockIdx.x >> 5;
  int og = blockIdx.x & 31;
  int o0 = og * 8;
  int t = threadIdx.x;
  __shared__ float ldsf[5][8][MROW];  // [arr][o_l][288 floats: c32 x tap9]
  __shared__ float att_lds[128];
  if (t < 128) att_lds[t] = att[t];
  const float* bases[5] = {statw, weight, weight + 589824, weight + 2 * 589824,
                           weight + 3 * 589824};
#pragma unroll
  for (int i = 0; i < 9; ++i) {
    int L = i * 320 + t;  // 9*320 = 2880 exactly
    int a = L / 576;
    int r = L % 576;
    int o_l = r / 72;
    int q = r % 72;
    float4 v = *reinterpret_cast<const float4*>(bases[a] + (size_t)(o0 + o_l) * 2304 +
                                                cc * 288 + q * 4);
    float* d = &ldsf[a][o_l][q * 4];
    d[0] = v.x; d[1] = v.y; d[2] = v.z; d[3] = v.w;
  }
  __syncthreads();
  if (t < 288) {
    int o_l = t & 7;
    int cblk = (t >> 3) & 3;
    int tap = t >> 5;  // 0..8
    float sv[8], wk0[8], wk1[8], wk2[8], wk3[8];
#pragma unroll
    for (int cl = 0; cl < 8; ++cl) {
      int idx9 = (cblk * 8 + cl) * 9 + tap;
      sv[cl] = ldsf[0][o_l][idx9];
      wk0[cl] = ldsf[1][o_l][idx9];
      wk1[cl] = ldsf[2][o_l][idx9];
      wk2[cl] = ldsf[3][o_l][idx9];
      wk3[cl] = ldsf[4][o_l][idx9];
    }
    size_t obase = ((size_t)(tap * 8 + cc) * 4 + cblk) * 256 + (o0 + o_l);
    for (int b = 0; b < 32; ++b) {
      float a0 = 0.1f * att_lds[b * 4 + 0];
      float a1 = 0.1f * att_lds[b * 4 + 1];
      float a2 = 0.1f * att_lds[b * 4 + 2];
      float a3 = 0.1f * att_lds[b * 4 + 3];
      ushort8 outv;
#pragma unroll
      for (int cl = 0; cl < 8; ++cl) {
        float v = sv[cl] + a0 * wk0[cl] + a1 * wk1[cl] + a2 * wk2[cl] + a3 * wk3[cl];
        outv[cl] = f2bf(v);
      }
      *reinterpret_cast<ushort8*>(agg + ((size_t)b * 73728 + obase) * 8) = outv;
    }
  }
}

// ---------- kernel 4: implicit-GEMM conv; 4x1 wave grid, no setprio (m190), no stagger ----
// grid 512 = 32 b * 2 ot * 8 pt ; block 256 = 4 waves stacked in o; tile 128(o) x 128(hw).
// Each wave owns a distinct 32-o strip (unique A per wave). X frags: 8 ds_read_b128 per tap.
__global__ __launch_bounds__(256, 2) void conv_kernel(
    const unsigned short* __restrict__ xpad, const unsigned short* __restrict__ agg,
    float* __restrict__ out) {
  int wgid = (blockIdx.x & 7) * 64 + (blockIdx.x >> 3);  // XCD-bijective: 8 XCD * 64
  int k = wgid & 63;
  int b = (wgid >> 6) * 4 + (k & 3);
  int ot = (k >> 2) & 1;
  int pt = k >> 3;
  int h0 = pt * 4;

  __shared__ __align__(16) unsigned short x_lds[2][8192];  // dbuf [cblk][6r*34w*8c(+slack)]

  int tid = threadIdx.x;
  int lane = tid & 63, wv = tid >> 6;
  int wave_mo = wv * 32;  // distinct 32-o strip per wave
  int kb = lane >> 4, ln = lane & 15;

  f32x4 acc[2][8];
#pragma unroll
  for (int i = 0; i < 2; ++i)
#pragma unroll
    for (int j = 0; j < 8; ++j) acc[i][j] = (f32x4){0.f, 0.f, 0.f, 0.f};

  // per-lane A base: agg[b][tap][cc][cblk=kb][o = ot*128 + wave_mo + ai*16 + ln][8c]
  const unsigned short* aggL =
      agg + (size_t)b * 589824 + ((size_t)kb * 256 + ot * 128 + wave_mo + ln) * 8;
  auto loadA = [&](int tg, bf16x8* dst) {  // dst[ai], ai<2 ; o+16 rows = +128 shorts
    const unsigned short* g = aggL + (size_t)tg * 8192;
    dst[0] = *reinterpret_cast<const bf16x8*>(g);
    dst[1] = *reinterpret_cast<const bf16x8*>(g + 128);
  };

  auto issueX = [&](int cc, int bsel) {
    const unsigned short* g = xpad + ((size_t)(b * 32 + cc * 4 + wv) * 1156 + h0 * 34) * 8;
    unsigned short* l = &x_lds[bsel][wv * 2048];
#pragma unroll
    for (int i = 0; i < 4; ++i) gload_lds16(g + i * 512 + lane * 8, l + i * 512);
  };

  issueX(0, 0);
  __syncthreads();  // X(0) resident

#pragma unroll 1
  for (int cc = 0; cc < 8; ++cc) {
    const unsigned short* xb = &x_lds[cc & 1][kb * 2048];
    bf16x8 af[2], afn[2];
    loadA(cc, af);  // tap 0 (tg = tap*8+cc)
#pragma unroll
    for (int tap = 0; tap < 9; ++tap) {
      if (tap < 8) loadA((tap + 1) * 8 + cc, afn);  // 1-tap A prefetch
      if (tap == 7 && cc < 7) issueX(cc + 1, (cc + 1) & 1);  // younger than afn waits
      int dh = tap / 3, dw = tap % 3;
      bf16x8 bfr[8];
#pragma unroll
      for (int bj = 0; bj < 8; ++bj) {
        int p = bj * 16 + ln;  // full 128-hw extent
        int rr = (p >> 5) + dh;
        int wc = (p & 31) + dw;
        bfr[bj] = *reinterpret_cast<const bf16x8*>(xb + (rr * 34 + wc) * 8);
      }
#pragma unroll
      for (int ai = 0; ai < 2; ++ai)
#pragma unroll
        for (int bj = 0; bj < 8; ++bj)
          acc[ai][bj] =
              __builtin_amdgcn_mfma_f32_16x16x32_bf16(af[ai], bfr[bj], acc[ai][bj], 0, 0, 0);
      if (tap < 8) {
        af[0] = afn[0];
        af[1] = afn[1];
      }
    }
    __syncthreads();  // readers of x_lds[cc&1] done; X(cc+1) writes drained
  }

  // ---- epilogue: C/D layout col=lane&15 (hw), row=(lane>>4)*4+v (o) ----
  size_t ob = ((size_t)b * 256 + ot * 128 + wave_mo) * 1024 + (size_t)pt * 128;
#pragma unroll
  for (int ai = 0; ai < 2; ++ai)
#pragma unroll
    for (int bj = 0; bj < 8; ++bj) {
#pragma unroll
      for (int v = 0; v < 4; ++v) {
        int oo = ai * 16 + kb * 4 + v;
        out[ob + (size_t)oo * 1024 + bj * 16 + ln] = acc[ai][bj][v];
      }
    }
}

extern "C" void kernel_launch(void* const* d_in, const int* in_sizes, int n_in,
                              void* d_out, int out_size, void* d_ws, size_t ws_size,
                              hipStream_t stream) {
  const float* x = (const float*)d_in[0];
  const float* z = (const float*)d_in[1];
  const float* w1 = (const float*)d_in[2];
  const float* gamma = (const float*)d_in[3];
  const float* beta = (const float*)d_in[4];
  const float* mean = (const float*)d_in[5];
  const float* var = (const float*)d_in[6];
  const float* w2 = (const float*)d_in[7];
  const float* weight = (const float*)d_in[8];
  const float* statw = (const float*)d_in[9];
  float* out = (float*)d_out;

  float* att = (float*)d_ws;                                       // 512 B
  float* avg = (float*)((char*)d_ws + 1024);                       // 32 KB
  unsigned short* xpad = (unsigned short*)((char*)d_ws + 65536);   // 18.94 MB (+slack)
  unsigned short* agg = (unsigned short*)((char*)d_ws + 19009536); // 37.75 MB

  prep_kernel<<<1024, 256, 0, stream>>>(x, avg, xpad);
  att_kernel<<<32, 256, 0, stream>>>(z, avg, w1, gamma, beta, mean, var, w2, att);
  mix_kernel<<<256, 320, 0, stream>>>(weight, statw, att, agg);
  conv_kernel<<<512, 256, 0, stream>>>(xpad, agg, out);
}

// Round 16
// 77.992 us; speedup vs baseline: 1.1823x; 1.1823x over previous
//
#include <hip/hip_runtime.h>
#include <hip/hip_bf16.h>

typedef __attribute__((ext_vector_type(4))) float f32x4;
typedef __attribute__((ext_vector_type(8))) short bf16x8;
typedef __attribute__((ext_vector_type(8))) unsigned short ushort8;

#define EPSBN 1e-5f

__device__ __forceinline__ unsigned short f2bf(float f) {
  unsigned int u = __builtin_bit_cast(unsigned int, f);
  u += 0x7fffu + ((u >> 16) & 1u);
  return (unsigned short)(u >> 16);
}

__device__ __forceinline__ void gload_lds16(const unsigned short* g, unsigned short* l) {
  __builtin_amdgcn_global_load_lds(
      (const __attribute__((address_space(1))) void*)g,
      (__attribute__((address_space(3))) void*)l, 16, 0, 0);
}

// ---------- kernel 1: fused avg-pool + x -> bf16 pre-padded staging layout ----------
// xpad layout: [b][cg(32)][h_pad(34)][w_pad(34)][8c] bf16, zero border.
__global__ __launch_bounds__(256) void prep_kernel(const float* __restrict__ x,
                                                   float* __restrict__ avg,
                                                   unsigned short* __restrict__ xpad) {
  int blk = blockIdx.x;  // b*32 + cg
  int b = blk >> 5, cg = blk & 31;
  int t = threadIdx.x;
  int c = t >> 5, l32 = t & 31;
  __shared__ unsigned short lds_t[1024 * 9];  // [p][c] with pad-9 row (conflict-break)
  __shared__ float avg_lds[8];
  const float4* xb4 = reinterpret_cast<const float4*>(x) + ((size_t)(b * 256 + cg * 8 + c)) * 256;
  float s = 0.f;
#pragma unroll
  for (int i = 0; i < 8; ++i) {
    float4 v = xb4[l32 + 32 * i];
    s += v.x + v.y + v.z + v.w;
    int p = 4 * (l32 + 32 * i);
    lds_t[(p + 0) * 9 + c] = f2bf(v.x);
    lds_t[(p + 1) * 9 + c] = f2bf(v.y);
    lds_t[(p + 2) * 9 + c] = f2bf(v.z);
    lds_t[(p + 3) * 9 + c] = f2bf(v.w);
  }
#pragma unroll
  for (int off = 16; off >= 1; off >>= 1) s += __shfl_down(s, off, 32);
  if (l32 == 0) avg_lds[c] = s;
  __syncthreads();
  if (t < 8) avg[b * 256 + cg * 8 + t] = avg_lds[t] * (1.0f / 1024.0f);
  size_t obase = (size_t)blk * 1156 * 8;
  for (int sIdx = t; sIdx < 1156; sIdx += 256) {
    int h = sIdx / 34, w = sIdx % 34;
    ushort8 v;
    if (h >= 1 && h <= 32 && w >= 1 && w <= 32) {
      int p = (h - 1) * 32 + (w - 1);
#pragma unroll
      for (int cl = 0; cl < 8; ++cl) v[cl] = lds_t[p * 9 + cl];
    } else {
#pragma unroll
      for (int cl = 0; cl < 8; ++cl) v[cl] = 0;
    }
    *reinterpret_cast<ushort8*>(xpad + obase + (size_t)sIdx * 8) = v;
  }
}

// ---------- kernel 2: attention head -> att[B][4] ----------
__global__ __launch_bounds__(256) void att_kernel(
    const float* __restrict__ z, const float* __restrict__ avg,
    const float* __restrict__ w1, const float* __restrict__ gamma,
    const float* __restrict__ beta, const float* __restrict__ mean,
    const float* __restrict__ var, const float* __restrict__ w2,
    float* __restrict__ att) {
  int b = blockIdx.x, t = threadIdx.x;
  __shared__ __align__(16) float a[512];
  __shared__ float h[256];
  a[t] = z[b * 256 + t];
  a[t + 256] = avg[b * 256 + t];
  __syncthreads();
  const float4* wr = reinterpret_cast<const float4*>(w1 + (size_t)t * 512);
  const float4* a4 = reinterpret_cast<const float4*>(a);
  float s = 0.f;
#pragma unroll 4
  for (int j = 0; j < 128; ++j) {
    float4 wv = wr[j], av = a4[j];
    s += wv.x * av.x + wv.y * av.y + wv.z * av.z + wv.w * av.w;
  }
  s = (s - mean[t]) * rsqrtf(var[t] + EPSBN) * gamma[t] + beta[t];
  h[t] = fmaxf(s, 0.f);
  __syncthreads();
  int wv_ = t >> 6, lane = t & 63;
  const float* w2r = w2 + wv_ * 256;
  float p = h[lane] * w2r[lane] + h[lane + 64] * w2r[lane + 64] +
            h[lane + 128] * w2r[lane + 128] + h[lane + 192] * w2r[lane + 192];
#pragma unroll
  for (int off = 32; off >= 1; off >>= 1) p += __shfl_down(p, off);
  if (lane == 0) att[b * 4 + wv_] = 1.0f / (1.0f + expf(-p));
}

// ---------- kernel 3: mix weights via LDS transpose -> bf16 agg in conv A-layout ----------
// agg element index: ((((b*9+tap)*8+cc)*4+cblk)*256 + o)*8 + cl ; c = cc*32+cblk*8+cl
// 320 threads: phase1 = 9 exact float4 loads/thread; phase2 = 1 slot/thread (288 active).
#define MROW 291  // padded LDS row stride (floats) for bank decorrelation
__global__ __launch_bounds__(320) void mix_kernel(
    const float* __restrict__ weight, const float* __restrict__ statw,
    const float* __restrict__ att, unsigned short* __restrict__ agg) {
  int cc = blockIdx.x >> 5;
  int og = blockIdx.x & 31;
  int o0 = og * 8;
  int t = threadIdx.x;
  __shared__ float ldsf[5][8][MROW];  // [arr][o_l][288 floats: c32 x tap9]
  __shared__ float att_lds[128];
  if (t < 128) att_lds[t] = att[t];
  const float* bases[5] = {statw, weight, weight + 589824, weight + 2 * 589824,
                           weight + 3 * 589824};
#pragma unroll
  for (int i = 0; i < 9; ++i) {
    int L = i * 320 + t;  // 9*320 = 2880 exactly
    int a = L / 576;
    int r = L % 576;
    int o_l = r / 72;
    int q = r % 72;
    float4 v = *reinterpret_cast<const float4*>(bases[a] + (size_t)(o0 + o_l) * 2304 +
                                                cc * 288 + q * 4);
    float* d = &ldsf[a][o_l][q * 4];
    d[0] = v.x; d[1] = v.y; d[2] = v.z; d[3] = v.w;
  }
  __syncthreads();
  if (t < 288) {
    int o_l = t & 7;
    int cblk = (t >> 3) & 3;
    int tap = t >> 5;  // 0..8
    float sv[8], wk0[8], wk1[8], wk2[8], wk3[8];
#pragma unroll
    for (int cl = 0; cl < 8; ++cl) {
      int idx9 = (cblk * 8 + cl) * 9 + tap;
      sv[cl] = ldsf[0][o_l][idx9];
      wk0[cl] = ldsf[1][o_l][idx9];
      wk1[cl] = ldsf[2][o_l][idx9];
      wk2[cl] = ldsf[3][o_l][idx9];
      wk3[cl] = ldsf[4][o_l][idx9];
    }
    size_t obase = ((size_t)(tap * 8 + cc) * 4 + cblk) * 256 + (o0 + o_l);
    for (int b = 0; b < 32; ++b) {
      float a0 = 0.1f * att_lds[b * 4 + 0];
      float a1 = 0.1f * att_lds[b * 4 + 1];
      float a2 = 0.1f * att_lds[b * 4 + 2];
      float a3 = 0.1f * att_lds[b * 4 + 3];
      ushort8 outv;
#pragma unroll
      for (int cl = 0; cl < 8; ++cl) {
        float v = sv[cl] + a0 * wk0[cl] + a1 * wk1[cl] + a2 * wk2[cl] + a3 * wk3[cl];
        outv[cl] = f2bf(v);
      }
      *reinterpret_cast<ushort8*>(agg + ((size_t)b * 73728 + obase) * 8) = outv;
    }
  }
}

// ---------- kernel 4: implicit-GEMM conv; 4x1 wave grid + setprio (R13-proven best) ----------
// grid 512 = 32 b * 2 ot * 8 pt ; block 256 = 4 waves stacked in o; tile 128(o) x 128(hw).
// Each wave owns a distinct 32-o strip (unique A per wave). A reg-staged via global loads
// (role-split per wave -> T5 setprio pays: removing it cost 20%, R15). X: LDS dbuf per cc.
__global__ __launch_bounds__(256, 2) void conv_kernel(
    const unsigned short* __restrict__ xpad, const unsigned short* __restrict__ agg,
    float* __restrict__ out) {
  int wgid = (blockIdx.x & 7) * 64 + (blockIdx.x >> 3);  // XCD-bijective: 8 XCD * 64
  int k = wgid & 63;
  int b = (wgid >> 6) * 4 + (k & 3);
  int ot = (k >> 2) & 1;
  int pt = k >> 3;
  int h0 = pt * 4;

  __shared__ __align__(16) unsigned short x_lds[2][8192];  // dbuf [cblk][6r*34w*8c(+slack)]

  int tid = threadIdx.x;
  int lane = tid & 63, wv = tid >> 6;
  int wave_mo = wv * 32;  // distinct 32-o strip per wave
  int kb = lane >> 4, ln = lane & 15;

  f32x4 acc[2][8];
#pragma unroll
  for (int i = 0; i < 2; ++i)
#pragma unroll
    for (int j = 0; j < 8; ++j) acc[i][j] = (f32x4){0.f, 0.f, 0.f, 0.f};

  // per-lane A base: agg[b][tap][cc][cblk=kb][o = ot*128 + wave_mo + ai*16 + ln][8c]
  const unsigned short* aggL =
      agg + (size_t)b * 589824 + ((size_t)kb * 256 + ot * 128 + wave_mo + ln) * 8;
  auto loadA = [&](int tg, bf16x8* dst) {  // dst[ai], ai<2 ; o+16 rows = +128 shorts
    const unsigned short* g = aggL + (size_t)tg * 8192;
    dst[0] = *reinterpret_cast<const bf16x8*>(g);
    dst[1] = *reinterpret_cast<const bf16x8*>(g + 128);
  };

  auto issueX = [&](int cc, int bsel) {
    const unsigned short* g = xpad + ((size_t)(b * 32 + cc * 4 + wv) * 1156 + h0 * 34) * 8;
    unsigned short* l = &x_lds[bsel][wv * 2048];
#pragma unroll
    for (int i = 0; i < 4; ++i) gload_lds16(g + i * 512 + lane * 8, l + i * 512);
  };

  issueX(0, 0);
  __syncthreads();  // X(0) resident

#pragma unroll 1
  for (int cc = 0; cc < 8; ++cc) {
    const unsigned short* xb = &x_lds[cc & 1][kb * 2048];
    bf16x8 af[2], afn[2];
    loadA(cc, af);  // tap 0 (tg = tap*8+cc)
#pragma unroll
    for (int tap = 0; tap < 9; ++tap) {
      if (tap < 8) loadA((tap + 1) * 8 + cc, afn);  // 1-tap A prefetch
      if (tap == 7 && cc < 7) issueX(cc + 1, (cc + 1) & 1);  // younger than afn waits
      int dh = tap / 3, dw = tap % 3;
      bf16x8 bfr[8];
#pragma unroll
      for (int bj = 0; bj < 8; ++bj) {
        int p = bj * 16 + ln;  // full 128-hw extent
        int rr = (p >> 5) + dh;
        int wc = (p & 31) + dw;
        bfr[bj] = *reinterpret_cast<const bf16x8*>(xb + (rr * 34 + wc) * 8);
      }
      __builtin_amdgcn_s_setprio(1);
#pragma unroll
      for (int ai = 0; ai < 2; ++ai)
#pragma unroll
        for (int bj = 0; bj < 8; ++bj)
          acc[ai][bj] =
              __builtin_amdgcn_mfma_f32_16x16x32_bf16(af[ai], bfr[bj], acc[ai][bj], 0, 0, 0);
      __builtin_amdgcn_s_setprio(0);
      if (tap < 8) {
        af[0] = afn[0];
        af[1] = afn[1];
      }
    }
    __syncthreads();  // readers of x_lds[cc&1] done; X(cc+1) writes drained
  }

  // ---- epilogue: C/D layout col=lane&15 (hw), row=(lane>>4)*4+v (o) ----
  size_t ob = ((size_t)b * 256 + ot * 128 + wave_mo) * 1024 + (size_t)pt * 128;
#pragma unroll
  for (int ai = 0; ai < 2; ++ai)
#pragma unroll
    for (int bj = 0; bj < 8; ++bj) {
#pragma unroll
      for (int v = 0; v < 4; ++v) {
        int oo = ai * 16 + kb * 4 + v;
        out[ob + (size_t)oo * 1024 + bj * 16 + ln] = acc[ai][bj][v];
      }
    }
}

extern "C" void kernel_launch(void* const* d_in, const int* in_sizes, int n_in,
                              void* d_out, int out_size, void* d_ws, size_t ws_size,
                              hipStream_t stream) {
  const float* x = (const float*)d_in[0];
  const float* z = (const float*)d_in[1];
  const float* w1 = (const float*)d_in[2];
  const float* gamma = (const float*)d_in[3];
  const float* beta = (const float*)d_in[4];
  const float* mean = (const float*)d_in[5];
  const float* var = (const float*)d_in[6];
  const float* w2 = (const float*)d_in[7];
  const float* weight = (const float*)d_in[8];
  const float* statw = (const float*)d_in[9];
  float* out = (float*)d_out;

  float* att = (float*)d_ws;                                       // 512 B
  float* avg = (float*)((char*)d_ws + 1024);                       // 32 KB
  unsigned short* xpad = (unsigned short*)((char*)d_ws + 65536);   // 18.94 MB (+slack)
  unsigned short* agg = (unsigned short*)((char*)d_ws + 19009536); // 37.75 MB

  prep_kernel<<<1024, 256, 0, stream>>>(x, avg, xpad);
  att_kernel<<<32, 256, 0, stream>>>(z, avg, w1, gamma, beta, mean, var, w2, att);
  mix_kernel<<<256, 320, 0, stream>>>(weight, statw, att, agg);
  conv_kernel<<<512, 256, 0, stream>>>(xpad, agg, out);
}